// Round 10
// baseline (782.468 us; speedup 1.0000x reference)
//
#include <hip/hip_runtime.h>
#include <hip/hip_fp16.h>

#define N_FEAT 128
#define HID 16
#define NPB 128          // nodes per bucket (7-bit local dst)
#define KMAX 1024        // max buckets (K = 782 here)
#define EPT 16           // edges per thread in bin_kernel
#define SPLIT 4          // blocks per bucket in agg

// ctrl ints: bstart@0 (KMAX+64) | gcursor@1088 (KMAX)
#define CTRL_INTS 2112

static __device__ __forceinline__ int ph2(float a, float b) {
    __half2 h = __floats2half2_rn(a, b);
    return *reinterpret_cast<int*>(&h);
}

// ================= node degree histogram (int) ============================
__global__ void degn_kernel(const int* __restrict__ dst,
                            int* __restrict__ deg, int E) {
    int i = blockIdx.x * blockDim.x + threadIdx.x;
    int base = i * 4;
    if (base + 3 < E) {
        int4 d = ((const int4*)dst)[i];
        atomicAdd(&deg[d.x], 1);
        atomicAdd(&deg[d.y], 1);
        atomicAdd(&deg[d.z], 1);
        atomicAdd(&deg[d.w], 1);
    } else {
        for (int e = base; e < E; ++e) atomicAdd(&deg[dst[e]], 1);
    }
}

// ===== bucket sums from deg + exclusive scan (single block, 1024 thr) =====
__global__ void bscan2_kernel(const int* __restrict__ deg,   // nal ints, 0-padded
                              int* __restrict__ bstart,
                              int* __restrict__ gcursor, int K, int E) {
    __shared__ int l[KMAX];
    int t = threadIdx.x;
    int sum = 0;
    if (t < K) {
        const int4* d4 = (const int4*)deg + t * (NPB / 4);
#pragma unroll
        for (int i = 0; i < NPB / 4; ++i) {
            int4 v = d4[i];
            sum += v.x + v.y + v.z + v.w;
        }
    }
    l[t] = sum;
    __syncthreads();
    for (int off = 1; off < KMAX; off <<= 1) {
        int tmp = (t >= off) ? l[t - off] : 0;
        __syncthreads();
        l[t] += tmp;
        __syncthreads();
    }
    int excl = l[t] - sum;          // == E for t >= K
    bstart[t]  = excl;
    gcursor[t] = excl;
    if (t == 0) bstart[KMAX] = E;
}

// ================= dinv[v] = rsqrt(deg[v]+1) ==============================
__global__ void dinv_kernel(const int* __restrict__ deg,
                            float* __restrict__ dinv, int n) {
    int v = blockIdx.x * blockDim.x + threadIdx.x;
    if (v < n) dinv[v] = rsqrtf((float)deg[v] + 1.0f);
}

// ===== one-level binning, register-staged coalesced flush (round-5) =======
__global__ void bin_kernel(const int* __restrict__ src,
                           const int* __restrict__ dst,
                           int* __restrict__ gcursor,
                           int* __restrict__ binned, int E) {
    __shared__ int rcnt[KMAX];
    __shared__ int rbase[KMAX];
    int base = blockIdx.x * (256 * EPT);
    if (base >= E) return;

    for (int i = threadIdx.x; i < KMAX; i += 256) rcnt[i] = 0;
    __syncthreads();

    int myb[EPT], myoff[EPT], mypack[EPT];
#pragma unroll
    for (int q = 0; q < EPT; ++q) {
        int e = base + q * 256 + threadIdx.x;
        myb[q] = -1;
        if (e < E) {
            int d = dst[e], s = src[e];
            int b = d >> 7;
            myb[q]    = b;
            mypack[q] = ((d & 127) << 17) | s;
            myoff[q]  = atomicAdd(&rcnt[b], 1);
        }
    }
    __syncthreads();
    for (int i = threadIdx.x; i < KMAX; i += 256) {
        int c = rcnt[i];
        if (c > 0) rbase[i] = atomicAdd(&gcursor[i], c);
    }
    __syncthreads();
#pragma unroll
    for (int q = 0; q < EPT; ++q)
        if (myb[q] >= 0) binned[rbase[myb[q]] + myoff[q]] = mypack[q];
}

// ========= xform1: g1h[v,:] = fp16((x[v,:] @ W1) * dinv[v]) ===============
__global__ void xform1_kernel(const float* __restrict__ x,
                              const float* __restrict__ W1,
                              const float* __restrict__ dinv,
                              int4* __restrict__ g1h, int n) {
    __shared__ float Ws[N_FEAT * HID];
    for (int i = threadIdx.x; i < N_FEAT * HID; i += blockDim.x)
        Ws[i] = W1[i];
    __syncthreads();

    int v = blockIdx.x * blockDim.x + threadIdx.x;
    if (v >= n) return;

    float acc[HID];
#pragma unroll
    for (int j = 0; j < HID; ++j) acc[j] = 0.0f;

    const float4* xr = (const float4*)(x + (size_t)v * N_FEAT);
#pragma unroll
    for (int k4 = 0; k4 < N_FEAT / 4; ++k4) {
        float4 xv = xr[k4];
        int k = k4 * 4;
#pragma unroll
        for (int j = 0; j < HID; ++j) {
            acc[j] += xv.x * Ws[(k + 0) * HID + j]
                    + xv.y * Ws[(k + 1) * HID + j]
                    + xv.z * Ws[(k + 2) * HID + j]
                    + xv.w * Ws[(k + 3) * HID + j];
        }
    }
    float dv = dinv[v];
    int4 w0, w1;
    w0.x = ph2(acc[0] * dv,  acc[1] * dv);
    w0.y = ph2(acc[2] * dv,  acc[3] * dv);
    w0.z = ph2(acc[4] * dv,  acc[5] * dv);
    w0.w = ph2(acc[6] * dv,  acc[7] * dv);
    w1.x = ph2(acc[8] * dv,  acc[9] * dv);
    w1.y = ph2(acc[10] * dv, acc[11] * dv);
    w1.z = ph2(acc[12] * dv, acc[13] * dv);
    w1.w = ph2(acc[14] * dv, acc[15] * dv);
    g1h[(size_t)v * 2 + 0] = w0;
    g1h[(size_t)v * 2 + 1] = w1;
}

// ===== edge-parallel aggregation: 8 lanes/edge coalesced fp16 gather,
//       LDS fp32 accumulator per bucket-quarter, plain partial writes ======
__global__ __launch_bounds__(256) void agg_lds_kernel(
        const int* __restrict__ bstart,
        const int* __restrict__ binned,
        const unsigned* __restrict__ gh,   // 8 uints (16 fp16) per node
        float* __restrict__ apart,         // [SPLIT][pstride]
        size_t pstride) {
    __shared__ float acc[NPB * HID];       // 8 KB
    int b = blockIdx.x >> 2, q = blockIdx.x & 3;
    int rs = bstart[b], re = bstart[b + 1];
    int len = re - rs;
    int qs = rs + (int)(((long long)len * q) >> 2);
    int qe = rs + (int)(((long long)len * (q + 1)) >> 2);

    for (int i = threadIdx.x; i < NPB * HID; i += 256) acc[i] = 0.0f;
    __syncthreads();

    int j2 = threadIdx.x & 7;
    for (int e0 = qs + (threadIdx.x >> 3); e0 < qe; e0 += 64) {
        int eB = e0 + 32;
        bool vB = eB < qe;
        int pA = binned[e0];
        int pB = vB ? binned[eB] : 0;
        unsigned wA = gh[(size_t)(pA & 0x1FFFF) * 8 + j2];
        unsigned wB = vB ? gh[(size_t)(pB & 0x1FFFF) * 8 + j2] : 0u;
        float2 fA = __half22float2(*(__half2*)&wA);
        atomicAdd(&acc[(pA >> 17) * HID + j2 * 2],     fA.x);
        atomicAdd(&acc[(pA >> 17) * HID + j2 * 2 + 1], fA.y);
        if (vB) {
            float2 fB = __half22float2(*(__half2*)&wB);
            atomicAdd(&acc[(pB >> 17) * HID + j2 * 2],     fB.x);
            atomicAdd(&acc[(pB >> 17) * HID + j2 * 2 + 1], fB.y);
        }
    }
    __syncthreads();

    float* outp = apart + (size_t)q * pstride + (size_t)b * (NPB * HID);
    for (int i = threadIdx.x; i < NPB * HID; i += 256) outp[i] = acc[i];
}

// == fin1: t=relu(dv*(sum4+self)+b1); g2h = fp16(dv*(t@W2)) ================
__global__ void fin1_kernel(const float* __restrict__ apart, size_t pstride,
                            const int4* __restrict__ g1h,
                            const float* __restrict__ dinv,
                            const float* __restrict__ b1,
                            const float* __restrict__ W2,
                            int4* __restrict__ g2h, int n) {
    __shared__ float W2s[HID * HID];
    W2s[threadIdx.x] = W2[threadIdx.x];   // blockDim == 256
    __syncthreads();

    int v = blockIdx.x * 256 + threadIdx.x;
    if (v >= n) return;
    float dv = dinv[v];

    const float4* p0 = (const float4*)(apart + (size_t)v * HID);
    const float4* p1 = (const float4*)(apart + pstride + (size_t)v * HID);
    const float4* p2 = (const float4*)(apart + 2 * pstride + (size_t)v * HID);
    const float4* p3 = (const float4*)(apart + 3 * pstride + (size_t)v * HID);

    int4 s0 = g1h[(size_t)v * 2 + 0];
    int4 s1 = g1h[(size_t)v * 2 + 1];
    const __half2* hp0 = (const __half2*)&s0;
    const __half2* hp1 = (const __half2*)&s1;
    float self[HID];
#pragma unroll
    for (int qq = 0; qq < 4; ++qq) {
        float2 f = __half22float2(hp0[qq]);
        self[qq * 2] = f.x; self[qq * 2 + 1] = f.y;
    }
#pragma unroll
    for (int qq = 0; qq < 4; ++qq) {
        float2 f = __half22float2(hp1[qq]);
        self[8 + qq * 2] = f.x; self[8 + qq * 2 + 1] = f.y;
    }

    float t[HID];
#pragma unroll
    for (int qq = 0; qq < 4; ++qq) {
        float4 a = p0[qq], b = p1[qq], c = p2[qq], d = p3[qq];
        float sx = (a.x + b.x) + (c.x + d.x);
        float sy = (a.y + b.y) + (c.y + d.y);
        float sz = (a.z + b.z) + (c.z + d.z);
        float sw = (a.w + b.w) + (c.w + d.w);
        t[qq * 4 + 0] = fmaxf(dv * (sx + self[qq * 4 + 0]) + b1[qq * 4 + 0], 0.0f);
        t[qq * 4 + 1] = fmaxf(dv * (sy + self[qq * 4 + 1]) + b1[qq * 4 + 1], 0.0f);
        t[qq * 4 + 2] = fmaxf(dv * (sz + self[qq * 4 + 2]) + b1[qq * 4 + 2], 0.0f);
        t[qq * 4 + 3] = fmaxf(dv * (sw + self[qq * 4 + 3]) + b1[qq * 4 + 3], 0.0f);
    }

    float hh[HID];
#pragma unroll
    for (int j2 = 0; j2 < HID; ++j2) {
        float s = 0.0f;
#pragma unroll
        for (int j = 0; j < HID; ++j) s += t[j] * W2s[j * HID + j2];
        hh[j2] = s * dv;
    }
    int4 w0, w1;
    w0.x = ph2(hh[0], hh[1]);   w0.y = ph2(hh[2], hh[3]);
    w0.z = ph2(hh[4], hh[5]);   w0.w = ph2(hh[6], hh[7]);
    w1.x = ph2(hh[8], hh[9]);   w1.y = ph2(hh[10], hh[11]);
    w1.z = ph2(hh[12], hh[13]); w1.w = ph2(hh[14], hh[15]);
    g2h[(size_t)v * 2 + 0] = w0;
    g2h[(size_t)v * 2 + 1] = w1;
}

// == fin2: out = dv*(sum4 + self) + b2 =====================================
__global__ void fin2_kernel(const float* __restrict__ apart, size_t pstride,
                            const int4* __restrict__ g2h,
                            const float* __restrict__ dinv,
                            const float* __restrict__ b2,
                            float4* __restrict__ out, int n) {
    int v = blockIdx.x * 256 + threadIdx.x;
    if (v >= n) return;
    float dv = dinv[v];

    const float4* p0 = (const float4*)(apart + (size_t)v * HID);
    const float4* p1 = (const float4*)(apart + pstride + (size_t)v * HID);
    const float4* p2 = (const float4*)(apart + 2 * pstride + (size_t)v * HID);
    const float4* p3 = (const float4*)(apart + 3 * pstride + (size_t)v * HID);

    int4 s0 = g2h[(size_t)v * 2 + 0];
    int4 s1 = g2h[(size_t)v * 2 + 1];
    const __half2* hp0 = (const __half2*)&s0;
    const __half2* hp1 = (const __half2*)&s1;
    const float4* b24 = (const float4*)b2;

#pragma unroll
    for (int qq = 0; qq < 4; ++qq) {
        float4 a = p0[qq], b = p1[qq], c = p2[qq], d = p3[qq];
        float2 f0 = __half22float2(qq < 2 ? hp0[qq * 2] : hp1[(qq - 2) * 2]);
        float2 f1 = __half22float2(qq < 2 ? hp0[qq * 2 + 1] : hp1[(qq - 2) * 2 + 1]);
        float4 bb = b24[qq];
        float4 o;
        o.x = dv * ((a.x + b.x) + (c.x + d.x) + f0.x) + bb.x;
        o.y = dv * ((a.y + b.y) + (c.y + d.y) + f0.y) + bb.y;
        o.z = dv * ((a.z + b.z) + (c.z + d.z) + f1.x) + bb.z;
        o.w = dv * ((a.w + b.w) + (c.w + d.w) + f1.y) + bb.w;
        out[(size_t)v * 4 + qq] = o;
    }
}

// ========================= fallback (atomic, fp32) path ====================
__global__ void deg_kernel(const int* __restrict__ dst,
                           float* __restrict__ deg, int E) {
    int e = blockIdx.x * blockDim.x + threadIdx.x;
    if (e < E) atomicAdd(&deg[dst[e]], 1.0f);
}

__global__ void dinvf_kernel(float* __restrict__ deg, int n) {
    int v = blockIdx.x * blockDim.x + threadIdx.x;
    if (v < n) deg[v] = rsqrtf(deg[v] + 1.0f);
}

__global__ void agg_kernel(const int* __restrict__ src,
                           const int* __restrict__ dst,
                           const float* __restrict__ g,
                           float* __restrict__ acc, long long total) {
    long long i = (long long)blockIdx.x * blockDim.x + threadIdx.x;
    if (i >= total) return;
    int e = (int)(i >> 4);
    int j = (int)(i & 15);
    atomicAdd(&acc[(size_t)dst[e] * HID + j], g[(size_t)src[e] * HID + j]);
}

__global__ void xform1_flat_kernel(const float* __restrict__ x,
                                   const float* __restrict__ W1,
                                   const float* __restrict__ dinv,
                                   float* __restrict__ g1, int n) {
    __shared__ float Ws[N_FEAT * HID];
    for (int i = threadIdx.x; i < N_FEAT * HID; i += blockDim.x)
        Ws[i] = W1[i];
    __syncthreads();
    int v = blockIdx.x * blockDim.x + threadIdx.x;
    if (v >= n) return;
    float acc[HID];
#pragma unroll
    for (int j = 0; j < HID; ++j) acc[j] = 0.0f;
    const float4* xr = (const float4*)(x + (size_t)v * N_FEAT);
#pragma unroll
    for (int k4 = 0; k4 < N_FEAT / 4; ++k4) {
        float4 xv = xr[k4];
        int k = k4 * 4;
#pragma unroll
        for (int j = 0; j < HID; ++j) {
            acc[j] += xv.x * Ws[(k + 0) * HID + j]
                    + xv.y * Ws[(k + 1) * HID + j]
                    + xv.z * Ws[(k + 2) * HID + j]
                    + xv.w * Ws[(k + 3) * HID + j];
        }
    }
    float dv = dinv[v];
    float4* outp = (float4*)(g1 + (size_t)v * HID);
#pragma unroll
    for (int q = 0; q < HID / 4; ++q) {
        float4 o;
        o.x = acc[q * 4 + 0] * dv;
        o.y = acc[q * 4 + 1] * dv;
        o.z = acc[q * 4 + 2] * dv;
        o.w = acc[q * 4 + 3] * dv;
        outp[q] = o;
    }
}

__global__ void fin1_xform2_nolds_kernel(float* __restrict__ a1,
                                         const float* __restrict__ g1,
                                         const float* __restrict__ dinv,
                                         const float* __restrict__ b1,
                                         const float* __restrict__ W2,
                                         int n) {
    int v = blockIdx.x * blockDim.x + threadIdx.x;
    if (v >= n) return;
    float dv = dinv[v];
    const float4* a4 = (const float4*)(a1 + (size_t)v * HID);
    const float4* s4 = (const float4*)(g1 + (size_t)v * HID);
    float t[HID];
#pragma unroll
    for (int q = 0; q < HID / 4; ++q) {
        float4 av = a4[q];
        float4 sv = s4[q];
        t[q * 4 + 0] = fmaxf(dv * (av.x + sv.x) + b1[q * 4 + 0], 0.0f);
        t[q * 4 + 1] = fmaxf(dv * (av.y + sv.y) + b1[q * 4 + 1], 0.0f);
        t[q * 4 + 2] = fmaxf(dv * (av.z + sv.z) + b1[q * 4 + 2], 0.0f);
        t[q * 4 + 3] = fmaxf(dv * (av.w + sv.w) + b1[q * 4 + 3], 0.0f);
    }
    float4* outp = (float4*)(a1 + (size_t)v * HID);
#pragma unroll
    for (int q = 0; q < HID / 4; ++q) {
        float4 o;
        float h[4];
#pragma unroll
        for (int r = 0; r < 4; ++r) {
            int j2 = q * 4 + r;
            float acc = 0.0f;
#pragma unroll
            for (int j = 0; j < HID; ++j) acc += t[j] * W2[j * HID + j2];
            h[r] = acc * dv;
        }
        o.x = h[0]; o.y = h[1]; o.z = h[2]; o.w = h[3];
        outp[q] = o;
    }
}

__global__ void fin2f_kernel(float* __restrict__ out,
                             const float* __restrict__ g2,
                             const float* __restrict__ dinv,
                             const float* __restrict__ b2, int n) {
    int v = blockIdx.x * blockDim.x + threadIdx.x;
    if (v >= n) return;
    float dv = dinv[v];
    float4* o4 = (float4*)(out + (size_t)v * HID);
    const float4* g4 = (const float4*)(g2 + (size_t)v * HID);
#pragma unroll
    for (int q = 0; q < HID / 4; ++q) {
        float4 ov = o4[q];
        float4 gv = g4[q];
        float4 r;
        r.x = dv * (ov.x + gv.x) + b2[q * 4 + 0];
        r.y = dv * (ov.y + gv.y) + b2[q * 4 + 1];
        r.z = dv * (ov.z + gv.z) + b2[q * 4 + 2];
        r.w = dv * (ov.w + gv.w) + b2[q * 4 + 3];
        o4[q] = r;
    }
}

// ===========================================================================
extern "C" void kernel_launch(void* const* d_in, const int* in_sizes, int n_in,
                              void* d_out, int out_size, void* d_ws, size_t ws_size,
                              hipStream_t stream) {
    const float* x  = (const float*)d_in[0];
    const int*   ei = (const int*)d_in[1];     // int32 (JAX x64 disabled)
    const float* W1 = (const float*)d_in[2];
    const float* b1 = (const float*)d_in[3];
    const float* W2 = (const float*)d_in[4];
    const float* b2 = (const float*)d_in[5];
    float* out = (float*)d_out;

    const int n = in_sizes[0] / N_FEAT;         // 100000
    const int E = in_sizes[1] / 2;              // 3200000
    const int* src = ei;
    const int* dst = ei + E;

    const int B = 256;
    size_t nal = ((size_t)n + 255) & ~(size_t)255;
    const int K = (n + NPB - 1) / NPB;          // 782 buckets

    // ws: binned(E) | ctrl(2112) | deg(nal) | dinv(nal) | g1h(8nal) |
    //     g2h(8nal) | apart(4*16nal)
    size_t need = ((size_t)E + CTRL_INTS + 82 * nal) * sizeof(int);

    if (ws_size >= need && K <= KMAX) {
        int*      binned  = (int*)d_ws;                  // E
        int*      ctrl    = binned + E;                  // CTRL_INTS
        int*      bstart  = ctrl;                        // KMAX+64
        int*      gcursor = ctrl + KMAX + 64;            // KMAX
        int*      deg     = ctrl + CTRL_INTS;            // nal
        float*    dinv    = (float*)(deg + nal);         // nal
        int4*     g1h     = (int4*)(dinv + nal);         // 8nal ints
        int4*     g2h     = g1h + 2 * nal;               // 8nal ints
        float*    apart   = (float*)(g2h + 2 * nal);     // 64nal floats
        size_t    pstride = 16 * nal;

        hipMemsetAsync(deg, 0, nal * sizeof(int), stream);

        degn_kernel<<<(E / 4 + B - 1) / B, B, 0, stream>>>(dst, deg, E);
        bscan2_kernel<<<1, KMAX, 0, stream>>>(deg, bstart, gcursor, K, E);
        dinv_kernel<<<(n + B - 1) / B, B, 0, stream>>>(deg, dinv, n);

        int nblk = (E + 256 * EPT - 1) / (256 * EPT);
        bin_kernel<<<nblk, 256, 0, stream>>>(src, dst, gcursor, binned, E);

        xform1_kernel<<<(n + B - 1) / B, B, 0, stream>>>(x, W1, dinv, g1h, n);

        agg_lds_kernel<<<K * SPLIT, 256, 0, stream>>>(bstart, binned,
                                                      (const unsigned*)g1h,
                                                      apart, pstride);
        fin1_kernel<<<(n + 255) / 256, 256, 0, stream>>>(apart, pstride, g1h,
                                                         dinv, b1, W2, g2h, n);
        agg_lds_kernel<<<K * SPLIT, 256, 0, stream>>>(bstart, binned,
                                                      (const unsigned*)g2h,
                                                      apart, pstride);
        fin2_kernel<<<(n + 255) / 256, 256, 0, stream>>>(apart, pstride, g2h,
                                                         dinv, b2,
                                                         (float4*)out, n);
    } else {
        // fallback: proven atomic path (fp32)
        float* w   = (float*)d_ws;
        float* deg = w;                  // nal  (becomes dinv)
        float* a1  = w + nal;            // 16*nal (becomes g2)
        float* g1  = a1 + 16 * nal;      // 16*nal

        hipMemsetAsync(d_ws, 0, (nal * 17) * sizeof(float), stream);
        hipMemsetAsync(d_out, 0, (size_t)out_size * sizeof(float), stream);

        deg_kernel<<<(E + B - 1) / B, B, 0, stream>>>(dst, deg, E);
        dinvf_kernel<<<(n + B - 1) / B, B, 0, stream>>>(deg, n);
        xform1_flat_kernel<<<(n + B - 1) / B, B, 0, stream>>>(x, W1, deg, g1, n);
        long long total = (long long)E * HID;
        agg_kernel<<<(int)((total + B - 1) / B), B, 0, stream>>>(src, dst, g1, a1, total);
        fin1_xform2_nolds_kernel<<<(n + B - 1) / B, B, 0, stream>>>(a1, g1, deg, b1, W2, n);
        agg_kernel<<<(int)((total + B - 1) / B), B, 0, stream>>>(src, dst, a1, out, total);
        fin2f_kernel<<<(n + B - 1) / B, B, 0, stream>>>(out, a1, deg, b2, n);
    }
}

// Round 12
// 325.051 us; speedup vs baseline: 2.4072x; 2.4072x over previous
//
#include <hip/hip_runtime.h>

#define N_FEAT 128
#define HID 16
#define NPB 128          // nodes per bucket (7-bit local dst)
#define KMAX 1024        // max buckets (K = 782 here)
#define SEGCAP 8192      // max edges per bucket in sort LDS (mean 4096, sd 64)
#define EPT 16           // edges per thread in bin_kernel (782 blocks, PROVEN)
#define BATCH 16         // parallel gathers per batch in agg kernels

// ctrl ints: bstart@0 (KMAX+64) | gcursor@1088 (KMAX)
#define CTRL_INTS 2112

// ================= node degree histogram (int, 4-wide) ====================
__global__ void degn_kernel(const int* __restrict__ dst,
                            int* __restrict__ deg, int E) {
    int i = blockIdx.x * blockDim.x + threadIdx.x;
    int base = i * 4;
    if (base + 3 < E) {
        int4 d = ((const int4*)dst)[i];
        atomicAdd(&deg[d.x], 1);
        atomicAdd(&deg[d.y], 1);
        atomicAdd(&deg[d.z], 1);
        atomicAdd(&deg[d.w], 1);
    } else {
        for (int e = base; e < E; ++e) atomicAdd(&deg[dst[e]], 1);
    }
}

// ===== bucket sums from deg + exclusive scan (single block, 1024 thr) =====
__global__ void bscan2_kernel(const int* __restrict__ deg,   // nal ints, 0-padded
                              int* __restrict__ bstart,
                              int* __restrict__ gcursor, int K, int E) {
    __shared__ int l[KMAX];
    int t = threadIdx.x;
    int sum = 0;
    if (t < K) {
        const int4* d4 = (const int4*)deg + t * (NPB / 4);
#pragma unroll
        for (int i = 0; i < NPB / 4; ++i) {
            int4 v = d4[i];
            sum += v.x + v.y + v.z + v.w;
        }
    }
    l[t] = sum;
    __syncthreads();
    for (int off = 1; off < KMAX; off <<= 1) {
        int tmp = (t >= off) ? l[t - off] : 0;
        __syncthreads();
        l[t] += tmp;
        __syncthreads();
    }
    int excl = l[t] - sum;          // == E for t >= K
    bstart[t]  = excl;
    gcursor[t] = excl;
    if (t == 0) bstart[KMAX] = E;
}

// ================= dinv[v] = rsqrt(deg[v]+1) ==============================
__global__ void dinv_kernel(const int* __restrict__ deg,
                            float* __restrict__ dinv, int n) {
    int v = blockIdx.x * blockDim.x + threadIdx.x;
    if (v < n) dinv[v] = rsqrtf((float)deg[v] + 1.0f);
}

// ===== one-level binning, register-staged coalesced flush (EPT=16) ========
__global__ void bin_kernel(const int* __restrict__ src,
                           const int* __restrict__ dst,
                           int* __restrict__ gcursor,
                           int* __restrict__ binned, int E) {
    __shared__ int rcnt[KMAX];
    __shared__ int rbase[KMAX];
    int base = blockIdx.x * (256 * EPT);
    if (base >= E) return;

    for (int i = threadIdx.x; i < KMAX; i += 256) rcnt[i] = 0;
    __syncthreads();

    int myb[EPT], myoff[EPT], mypack[EPT];
#pragma unroll
    for (int q = 0; q < EPT; ++q) {
        int e = base + q * 256 + threadIdx.x;
        myb[q] = -1;
        if (e < E) {
            int d = dst[e], s = src[e];
            int b = d >> 7;
            myb[q]    = b;
            mypack[q] = ((d & 127) << 17) | s;
            myoff[q]  = atomicAdd(&rcnt[b], 1);
        }
    }
    __syncthreads();
    for (int i = threadIdx.x; i < KMAX; i += 256) {
        int c = rcnt[i];
        if (c > 0) rbase[i] = atomicAdd(&gcursor[i], c);
    }
    __syncthreads();
#pragma unroll
    for (int q = 0; q < EPT; ++q)
        if (myb[q] >= 0) binned[rbase[myb[q]] + myoff[q]] = mypack[q];
}

// ===== per-bucket counting sort (in place) + row_start ====================
__global__ void sort_kernel(const int* __restrict__ bstart,
                            int* __restrict__ binned,
                            int* __restrict__ row_start, int n, int E) {
    __shared__ int seg[SEGCAP];
    __shared__ int cnt[NPB];
    __shared__ int excl[NPB];
    __shared__ int cur[NPB];
    int b = blockIdx.x;
    int rs = bstart[b], re = bstart[b + 1];
    int m = re - rs;
    if (m > SEGCAP) m = SEGCAP;
    int t = threadIdx.x;

    if (t < NPB) cnt[t] = 0;
    __syncthreads();

    for (int k = t; k < m; k += 256) {
        int p = binned[rs + k];
        seg[k] = p;
        atomicAdd(&cnt[p >> 17], 1);
    }
    __syncthreads();

    if (t < NPB) excl[t] = cnt[t];
    __syncthreads();
    for (int off = 1; off < NPB; off <<= 1) {
        int v = (t < NPB && t >= off) ? excl[t - off] : 0;
        __syncthreads();
        if (t < NPB) excl[t] += v;
        __syncthreads();
    }

    int vbase = b * NPB;
    if (t < NPB) {
        int e0 = excl[t] - cnt[t];
        cur[t] = e0;
        int v = vbase + t;
        if (v < n) row_start[v] = rs + e0;
    }
    if (b == 0 && t == 0) row_start[n] = E;
    __syncthreads();

    for (int k = t; k < m; k += 256) {
        int p = seg[k];
        int pos = rs + atomicAdd(&cur[p >> 17], 1);
        binned[pos] = p & 0x1FFFF;                 // sorted src
    }
}

// ================= xform1: g1[v,:] = (x[v,:] @ W1) * dinv[v] ==============
__global__ void xform1_kernel(const float* __restrict__ x,
                              const float* __restrict__ W1,
                              const float* __restrict__ dinv,
                              float* __restrict__ g1, int n) {
    __shared__ float Ws[N_FEAT * HID];
    for (int i = threadIdx.x; i < N_FEAT * HID; i += blockDim.x)
        Ws[i] = W1[i];
    __syncthreads();

    int v = blockIdx.x * blockDim.x + threadIdx.x;
    if (v >= n) return;

    float acc[HID];
#pragma unroll
    for (int j = 0; j < HID; ++j) acc[j] = 0.0f;

    const float4* xr = (const float4*)(x + (size_t)v * N_FEAT);
#pragma unroll
    for (int k4 = 0; k4 < N_FEAT / 4; ++k4) {
        float4 xv = xr[k4];
        int k = k4 * 4;
#pragma unroll
        for (int j = 0; j < HID; ++j) {
            acc[j] += xv.x * Ws[(k + 0) * HID + j]
                    + xv.y * Ws[(k + 1) * HID + j]
                    + xv.z * Ws[(k + 2) * HID + j]
                    + xv.w * Ws[(k + 3) * HID + j];
        }
    }
    float dv = dinv[v];
    float4* outp = (float4*)(g1 + (size_t)v * HID);
#pragma unroll
    for (int q = 0; q < HID / 4; ++q) {
        float4 o;
        o.x = acc[q * 4 + 0] * dv;
        o.y = acc[q * 4 + 1] * dv;
        o.z = acc[q * 4 + 2] * dv;
        o.w = acc[q * 4 + 3] * dv;
        outp[q] = o;
    }
}

// ===== layer-1 aggregation: 4 lanes/node, 16 predicated parallel gathers ===
__global__ __launch_bounds__(256) void agg_raw_kernel(
        const int* __restrict__ row_start,
        const int* __restrict__ slots,
        const float4* __restrict__ g,      // 4 x float4 per node (64B row)
        float4* __restrict__ a, int n) {
    int v = blockIdx.x * 64 + (threadIdx.x >> 2);
    int h = threadIdx.x & 3;
    if (v >= n) return;

    int rs = row_start[v], re = row_start[v + 1];
    float4 s0 = {0.f,0.f,0.f,0.f}, s1 = s0, s2 = s0, s3 = s0;

    for (int k = rs; k < re; k += BATCH) {
        int e[BATCH];
#pragma unroll
        for (int u = 0; u < BATCH; ++u)
            e[u] = slots[min(k + u, re - 1)];
        float4 t[BATCH];
#pragma unroll
        for (int u = 0; u < BATCH; ++u)
            t[u] = g[(size_t)e[u] * 4 + h];
#pragma unroll
        for (int u = 0; u < BATCH; ++u) {
            if (k + u < re) {
                if ((u & 3) == 0) { s0.x += t[u].x; s0.y += t[u].y; s0.z += t[u].z; s0.w += t[u].w; }
                else if ((u & 3) == 1) { s1.x += t[u].x; s1.y += t[u].y; s1.z += t[u].z; s1.w += t[u].w; }
                else if ((u & 3) == 2) { s2.x += t[u].x; s2.y += t[u].y; s2.z += t[u].z; s2.w += t[u].w; }
                else { s3.x += t[u].x; s3.y += t[u].y; s3.z += t[u].z; s3.w += t[u].w; }
            }
        }
    }
    float4 r;
    r.x = (s0.x + s1.x) + (s2.x + s3.x);
    r.y = (s0.y + s1.y) + (s2.y + s3.y);
    r.z = (s0.z + s1.z) + (s2.z + s3.z);
    r.w = (s0.w + s1.w) + (s2.w + s3.w);
    a[(size_t)v * 4 + h] = r;
}

// ====== fin1: t=relu(dv*(a+g1)+b1); g2 = dv*(t@W2)  (in place over a) =====
__global__ void fin1_xform2_kernel(float* __restrict__ a,   // sums in, g2 out
                                   const float* __restrict__ g1,
                                   const float* __restrict__ dinv,
                                   const float* __restrict__ b1,
                                   const float* __restrict__ W2,
                                   int n) {
    __shared__ float W2s[HID * HID];
    W2s[threadIdx.x] = W2[threadIdx.x];   // blockDim == 256
    __syncthreads();

    int v = blockIdx.x * blockDim.x + threadIdx.x;
    if (v >= n) return;
    float dv = dinv[v];
    const float4* a4 = (const float4*)(a + (size_t)v * HID);
    const float4* s4 = (const float4*)(g1 + (size_t)v * HID);
    float t[HID];
#pragma unroll
    for (int q = 0; q < HID / 4; ++q) {
        float4 av = a4[q];
        float4 sv = s4[q];
        t[q * 4 + 0] = fmaxf(dv * (av.x + sv.x) + b1[q * 4 + 0], 0.0f);
        t[q * 4 + 1] = fmaxf(dv * (av.y + sv.y) + b1[q * 4 + 1], 0.0f);
        t[q * 4 + 2] = fmaxf(dv * (av.z + sv.z) + b1[q * 4 + 2], 0.0f);
        t[q * 4 + 3] = fmaxf(dv * (av.w + sv.w) + b1[q * 4 + 3], 0.0f);
    }
    float4* outp = (float4*)(a + (size_t)v * HID);
#pragma unroll
    for (int q = 0; q < HID / 4; ++q) {
        float4 o;
        float h[4];
#pragma unroll
        for (int r = 0; r < 4; ++r) {
            int j2 = q * 4 + r;
            float acc = 0.0f;
#pragma unroll
            for (int j = 0; j < HID; ++j) acc += t[j] * W2s[j * HID + j2];
            h[r] = acc * dv;
        }
        o.x = h[0]; o.y = h[1]; o.z = h[2]; o.w = h[3];
        outp[q] = o;
    }
}

// ===== layer-2 aggregation + finalize + bias ==============================
__global__ __launch_bounds__(256) void agg_fin_kernel(
        const int* __restrict__ row_start,
        const int* __restrict__ slots,
        const float4* __restrict__ g,      // g2, 4 x float4 per node
        const float* __restrict__ dinv,
        const float* __restrict__ b2,
        float4* __restrict__ out, int n) {
    int v = blockIdx.x * 64 + (threadIdx.x >> 2);
    int h = threadIdx.x & 3;
    if (v >= n) return;

    int rs = row_start[v], re = row_start[v + 1];
    float4 s0 = {0.f,0.f,0.f,0.f}, s1 = s0, s2 = s0, s3 = s0;

    for (int k = rs; k < re; k += BATCH) {
        int e[BATCH];
#pragma unroll
        for (int u = 0; u < BATCH; ++u)
            e[u] = slots[min(k + u, re - 1)];
        float4 t[BATCH];
#pragma unroll
        for (int u = 0; u < BATCH; ++u)
            t[u] = g[(size_t)e[u] * 4 + h];
#pragma unroll
        for (int u = 0; u < BATCH; ++u) {
            if (k + u < re) {
                if ((u & 3) == 0) { s0.x += t[u].x; s0.y += t[u].y; s0.z += t[u].z; s0.w += t[u].w; }
                else if ((u & 3) == 1) { s1.x += t[u].x; s1.y += t[u].y; s1.z += t[u].z; s1.w += t[u].w; }
                else if ((u & 3) == 2) { s2.x += t[u].x; s2.y += t[u].y; s2.z += t[u].z; s2.w += t[u].w; }
                else { s3.x += t[u].x; s3.y += t[u].y; s3.z += t[u].z; s3.w += t[u].w; }
            }
        }
    }
    float4 acc;
    acc.x = (s0.x + s1.x) + (s2.x + s3.x);
    acc.y = (s0.y + s1.y) + (s2.y + s3.y);
    acc.z = (s0.z + s1.z) + (s2.z + s3.z);
    acc.w = (s0.w + s1.w) + (s2.w + s3.w);

    float dv = dinv[v];
    float4 self = g[(size_t)v * 4 + h];
    float4 bb = ((const float4*)b2)[h];
    float4 o;
    o.x = dv * (acc.x + self.x) + bb.x;
    o.y = dv * (acc.y + self.y) + bb.y;
    o.z = dv * (acc.z + self.z) + bb.z;
    o.w = dv * (acc.w + self.w) + bb.w;
    out[(size_t)v * 4 + h] = o;
}

// ========================= fallback (atomic, fp32) path ====================
__global__ void deg_kernel(const int* __restrict__ dst,
                           float* __restrict__ deg, int E) {
    int e = blockIdx.x * blockDim.x + threadIdx.x;
    if (e < E) atomicAdd(&deg[dst[e]], 1.0f);
}

__global__ void dinvf_kernel(float* __restrict__ deg, int n) {
    int v = blockIdx.x * blockDim.x + threadIdx.x;
    if (v < n) deg[v] = rsqrtf(deg[v] + 1.0f);
}

__global__ void agg_kernel(const int* __restrict__ src,
                           const int* __restrict__ dst,
                           const float* __restrict__ g,
                           float* __restrict__ acc, long long total) {
    long long i = (long long)blockIdx.x * blockDim.x + threadIdx.x;
    if (i >= total) return;
    int e = (int)(i >> 4);
    int j = (int)(i & 15);
    atomicAdd(&acc[(size_t)dst[e] * HID + j], g[(size_t)src[e] * HID + j]);
}

__global__ void fin1_xform2_nolds_kernel(float* __restrict__ a1,
                                         const float* __restrict__ g1,
                                         const float* __restrict__ dinv,
                                         const float* __restrict__ b1,
                                         const float* __restrict__ W2,
                                         int n) {
    int v = blockIdx.x * blockDim.x + threadIdx.x;
    if (v >= n) return;
    float dv = dinv[v];
    const float4* a4 = (const float4*)(a1 + (size_t)v * HID);
    const float4* s4 = (const float4*)(g1 + (size_t)v * HID);
    float t[HID];
#pragma unroll
    for (int q = 0; q < HID / 4; ++q) {
        float4 av = a4[q];
        float4 sv = s4[q];
        t[q * 4 + 0] = fmaxf(dv * (av.x + sv.x) + b1[q * 4 + 0], 0.0f);
        t[q * 4 + 1] = fmaxf(dv * (av.y + sv.y) + b1[q * 4 + 1], 0.0f);
        t[q * 4 + 2] = fmaxf(dv * (av.z + sv.z) + b1[q * 4 + 2], 0.0f);
        t[q * 4 + 3] = fmaxf(dv * (av.w + sv.w) + b1[q * 4 + 3], 0.0f);
    }
    float4* outp = (float4*)(a1 + (size_t)v * HID);
#pragma unroll
    for (int q = 0; q < HID / 4; ++q) {
        float4 o;
        float h[4];
#pragma unroll
        for (int r = 0; r < 4; ++r) {
            int j2 = q * 4 + r;
            float acc = 0.0f;
#pragma unroll
            for (int j = 0; j < HID; ++j) acc += t[j] * W2[j * HID + j2];
            h[r] = acc * dv;
        }
        o.x = h[0]; o.y = h[1]; o.z = h[2]; o.w = h[3];
        outp[q] = o;
    }
}

__global__ void fin2f_kernel(float* __restrict__ out,
                             const float* __restrict__ g2,
                             const float* __restrict__ dinv,
                             const float* __restrict__ b2, int n) {
    int v = blockIdx.x * blockDim.x + threadIdx.x;
    if (v >= n) return;
    float dv = dinv[v];
    float4* o4 = (float4*)(out + (size_t)v * HID);
    const float4* g4 = (const float4*)(g2 + (size_t)v * HID);
#pragma unroll
    for (int q = 0; q < HID / 4; ++q) {
        float4 ov = o4[q];
        float4 gv = g4[q];
        float4 r;
        r.x = dv * (ov.x + gv.x) + b2[q * 4 + 0];
        r.y = dv * (ov.y + gv.y) + b2[q * 4 + 1];
        r.z = dv * (ov.z + gv.z) + b2[q * 4 + 2];
        r.w = dv * (ov.w + gv.w) + b2[q * 4 + 3];
        o4[q] = r;
    }
}

// ===========================================================================
extern "C" void kernel_launch(void* const* d_in, const int* in_sizes, int n_in,
                              void* d_out, int out_size, void* d_ws, size_t ws_size,
                              hipStream_t stream) {
    const float* x  = (const float*)d_in[0];
    const int*   ei = (const int*)d_in[1];     // int32 (JAX x64 disabled)
    const float* W1 = (const float*)d_in[2];
    const float* b1 = (const float*)d_in[3];
    const float* W2 = (const float*)d_in[4];
    const float* b2 = (const float*)d_in[5];
    float* out = (float*)d_out;

    const int n = in_sizes[0] / N_FEAT;         // 100000
    const int E = in_sizes[1] / 2;              // 3200000
    const int* src = ei;
    const int* dst = ei + E;

    const int B = 256;
    size_t nal = ((size_t)n + 255) & ~(size_t)255;
    const int K = (n + NPB - 1) / NPB;          // 782 buckets

    // ws: binned(E) | ctrl(2112) | deg(nal) | row_start(nal+64) | dinv(nal) |
    //     g1(16nal) | a(16nal)
    size_t need = ((size_t)E + CTRL_INTS + 35 * nal + 64) * sizeof(int);

    if (ws_size >= need && K <= KMAX) {
        int*      binned    = (int*)d_ws;                // E
        int*      ctrl      = binned + E;                // CTRL_INTS
        int*      bstart    = ctrl;                      // KMAX+64
        int*      gcursor   = ctrl + KMAX + 64;          // KMAX
        int*      deg       = ctrl + CTRL_INTS;          // nal
        int*      row_start = deg + nal;                 // nal + 64
        float*    dinv      = (float*)(row_start + nal + 64); // nal
        float*    g1        = dinv + nal;                // 16*nal
        float*    a         = g1 + 16 * nal;             // 16*nal

        hipMemsetAsync(deg, 0, nal * sizeof(int), stream);

        degn_kernel<<<(E / 4 + B - 1) / B, B, 0, stream>>>(dst, deg, E);
        bscan2_kernel<<<1, KMAX, 0, stream>>>(deg, bstart, gcursor, K, E);
        dinv_kernel<<<(n + B - 1) / B, B, 0, stream>>>(deg, dinv, n);

        int nblk = (E + 256 * EPT - 1) / (256 * EPT);    // 782 blocks
        bin_kernel<<<nblk, 256, 0, stream>>>(src, dst, gcursor, binned, E);

        sort_kernel<<<K, 256, 0, stream>>>(bstart, binned, row_start, n, E);

        xform1_kernel<<<(n + B - 1) / B, B, 0, stream>>>(x, W1, dinv, g1, n);

        int nb64 = (n + 63) / 64;
        agg_raw_kernel<<<nb64, 256, 0, stream>>>(row_start, binned,
                                                 (const float4*)g1, (float4*)a, n);
        fin1_xform2_kernel<<<(n + B - 1) / B, B, 0, stream>>>(a, g1, dinv, b1, W2, n);
        agg_fin_kernel<<<nb64, 256, 0, stream>>>(row_start, binned,
                                                 (const float4*)a, dinv, b2,
                                                 (float4*)out, n);
    } else {
        // fallback: proven atomic path (fp32)
        float* w   = (float*)d_ws;
        float* deg = w;                  // nal  (becomes dinv)
        float* a1  = w + nal;            // 16*nal (becomes g2)
        float* g1  = a1 + 16 * nal;      // 16*nal

        hipMemsetAsync(d_ws, 0, (nal * 17) * sizeof(float), stream);
        hipMemsetAsync(d_out, 0, (size_t)out_size * sizeof(float), stream);

        deg_kernel<<<(E + B - 1) / B, B, 0, stream>>>(dst, deg, E);
        dinvf_kernel<<<(n + B - 1) / B, B, 0, stream>>>(deg, n);
        xform1_kernel<<<(n + B - 1) / B, B, 0, stream>>>(x, W1, deg, g1, n);
        long long total = (long long)E * HID;
        agg_kernel<<<(int)((total + B - 1) / B), B, 0, stream>>>(src, dst, g1, a1, total);
        fin1_xform2_nolds_kernel<<<(n + B - 1) / B, B, 0, stream>>>(a1, g1, deg, b1, W2, n);
        agg_kernel<<<(int)((total + B - 1) / B), B, 0, stream>>>(src, dst, a1, out, total);
        fin2f_kernel<<<(n + B - 1) / B, B, 0, stream>>>(out, a1, deg, b2, n);
    }
}

// Round 13
// 197.004 us; speedup vs baseline: 3.9718x; 1.6500x over previous
//
#include <hip/hip_runtime.h>

#define N_FEAT 128
#define HID 16
#define NPB 128          // nodes per fine bucket (7-bit local dst)
#define KMAX 1024        // max fine buckets (K = 782 here)
#define SEGCAP 8192      // max edges per fine bucket in sort LDS
#define EPT 16           // edges per thread in bin_kernel (782 blocks, PROVEN)
#define BATCH 16         // parallel gathers per batch in agg kernels

// ctrl region (ints): bcnt@0(1024) | bstart@1024(1056) | gcursorF@2080(1024)
#define CTRL_INTS 3584

// ================= fine histogram (dst>>7) ================================
__global__ void bhist_kernel(const int* __restrict__ dst,
                             int* __restrict__ bcnt, int E, int K) {
    __shared__ int h[KMAX];
    for (int i = threadIdx.x; i < KMAX; i += 256) h[i] = 0;
    __syncthreads();
    for (long long e = (long long)blockIdx.x * 256 + threadIdx.x; e < E;
         e += (long long)gridDim.x * 256)
        atomicAdd(&h[dst[e] >> 7], 1);
    __syncthreads();
    for (int i = threadIdx.x; i < K; i += 256)
        if (h[i]) atomicAdd(&bcnt[i], h[i]);
}

// ================= scan of fine-bucket counts =============================
__global__ void bscan_kernel(const int* __restrict__ bcnt,
                             int* __restrict__ bstart,
                             int* __restrict__ gcursorF, int K, int E) {
    __shared__ int l[KMAX];
    int t = threadIdx.x;
    int v = (t < K) ? bcnt[t] : 0;
    l[t] = v;
    __syncthreads();
    for (int off = 1; off < KMAX; off <<= 1) {
        int tmp = (t >= off) ? l[t - off] : 0;
        __syncthreads();
        l[t] += tmp;
        __syncthreads();
    }
    int excl = l[t] - v;
    bstart[t]   = excl;          // == E for t >= K
    gcursorF[t] = excl;
    if (t == 0) bstart[KMAX] = E;
}

// ===== one-level binning, register-staged coalesced flush (round-5) =======
__global__ void bin_kernel(const int* __restrict__ src,
                           const int* __restrict__ dst,
                           int* __restrict__ gcursor,
                           int* __restrict__ binned, int E) {
    __shared__ int rcnt[KMAX];
    __shared__ int rbase[KMAX];
    int base = blockIdx.x * (256 * EPT);
    if (base >= E) return;

    for (int i = threadIdx.x; i < KMAX; i += 256) rcnt[i] = 0;
    __syncthreads();

    int myb[EPT], myoff[EPT], mypack[EPT];
#pragma unroll
    for (int q = 0; q < EPT; ++q) {
        int e = base + q * 256 + threadIdx.x;
        myb[q] = -1;
        if (e < E) {
            int d = dst[e], s = src[e];
            int b = d >> 7;
            myb[q]    = b;
            mypack[q] = ((d & 127) << 17) | s;
            myoff[q]  = atomicAdd(&rcnt[b], 1);
        }
    }
    __syncthreads();
    for (int i = threadIdx.x; i < KMAX; i += 256) {
        int c = rcnt[i];
        if (c > 0) rbase[i] = atomicAdd(&gcursor[i], c);
    }
    __syncthreads();
#pragma unroll
    for (int q = 0; q < EPT; ++q)
        if (myb[q] >= 0) binned[rbase[myb[q]] + myoff[q]] = mypack[q];
}

// ===== per-fine-bucket counting sort (in place) + row_start + dinv ========
__global__ void sort_kernel(const int* __restrict__ bstart,
                            int* __restrict__ binned,
                            int* __restrict__ row_start,
                            float* __restrict__ dinv, int n, int E) {
    __shared__ int seg[SEGCAP];
    __shared__ int cnt[NPB];
    __shared__ int excl[NPB];
    __shared__ int cur[NPB];
    int b = blockIdx.x;
    int rs = bstart[b], re = bstart[b + 1];
    int m = re - rs;
    if (m > SEGCAP) m = SEGCAP;
    int t = threadIdx.x;

    if (t < NPB) cnt[t] = 0;
    __syncthreads();

    for (int k = t; k < m; k += 256) {
        int p = binned[rs + k];
        seg[k] = p;
        atomicAdd(&cnt[p >> 17], 1);
    }
    __syncthreads();

    if (t < NPB) excl[t] = cnt[t];
    __syncthreads();
    for (int off = 1; off < NPB; off <<= 1) {
        int v = (t < NPB && t >= off) ? excl[t - off] : 0;
        __syncthreads();
        if (t < NPB) excl[t] += v;
        __syncthreads();
    }

    int vbase = b * NPB;
    if (t < NPB) {
        int e0 = excl[t] - cnt[t];
        cur[t] = e0;
        int v = vbase + t;
        if (v < n) {
            row_start[v] = rs + e0;
            dinv[v] = rsqrtf((float)cnt[t] + 1.0f);
        }
    }
    if (b == 0 && t == 0) row_start[n] = E;
    __syncthreads();

    for (int k = t; k < m; k += 256) {
        int p = seg[k];
        int pos = rs + atomicAdd(&cur[p >> 17], 1);
        binned[pos] = p & 0x1FFFF;                 // sorted src
    }
}

// ================= xform1: g1[v,:] = (x[v,:] @ W1) * dinv[v] ==============
__global__ void xform1_kernel(const float* __restrict__ x,
                              const float* __restrict__ W1,
                              const float* __restrict__ dinv,
                              float* __restrict__ g1, int n) {
    __shared__ float Ws[N_FEAT * HID];
    for (int i = threadIdx.x; i < N_FEAT * HID; i += blockDim.x)
        Ws[i] = W1[i];
    __syncthreads();

    int v = blockIdx.x * blockDim.x + threadIdx.x;
    if (v >= n) return;

    float acc[HID];
#pragma unroll
    for (int j = 0; j < HID; ++j) acc[j] = 0.0f;

    const float4* xr = (const float4*)(x + (size_t)v * N_FEAT);
#pragma unroll
    for (int k4 = 0; k4 < N_FEAT / 4; ++k4) {
        float4 xv = xr[k4];
        int k = k4 * 4;
#pragma unroll
        for (int j = 0; j < HID; ++j) {
            acc[j] += xv.x * Ws[(k + 0) * HID + j]
                    + xv.y * Ws[(k + 1) * HID + j]
                    + xv.z * Ws[(k + 2) * HID + j]
                    + xv.w * Ws[(k + 3) * HID + j];
        }
    }
    float dv = dinv[v];
    float4* outp = (float4*)(g1 + (size_t)v * HID);
#pragma unroll
    for (int q = 0; q < HID / 4; ++q) {
        float4 o;
        o.x = acc[q * 4 + 0] * dv;
        o.y = acc[q * 4 + 1] * dv;
        o.z = acc[q * 4 + 2] * dv;
        o.w = acc[q * 4 + 3] * dv;
        outp[q] = o;
    }
}

// ===== layer-1 aggregation: 4 lanes/node, 16 predicated parallel gathers ===
__global__ __launch_bounds__(256) void agg_raw_kernel(
        const int* __restrict__ row_start,
        const int* __restrict__ slots,
        const float4* __restrict__ g,      // 4 x float4 per node (64B row)
        float4* __restrict__ a, int n) {
    int v = blockIdx.x * 64 + (threadIdx.x >> 2);
    int h = threadIdx.x & 3;
    if (v >= n) return;

    int rs = row_start[v], re = row_start[v + 1];
    float4 s0 = {0.f,0.f,0.f,0.f}, s1 = s0, s2 = s0, s3 = s0;

    for (int k = rs; k < re; k += BATCH) {
        int e[BATCH];
#pragma unroll
        for (int u = 0; u < BATCH; ++u)
            e[u] = slots[min(k + u, re - 1)];
        float4 t[BATCH];
#pragma unroll
        for (int u = 0; u < BATCH; ++u)
            t[u] = g[(size_t)e[u] * 4 + h];
#pragma unroll
        for (int u = 0; u < BATCH; ++u) {
            if (k + u < re) {
                if ((u & 3) == 0) { s0.x += t[u].x; s0.y += t[u].y; s0.z += t[u].z; s0.w += t[u].w; }
                else if ((u & 3) == 1) { s1.x += t[u].x; s1.y += t[u].y; s1.z += t[u].z; s1.w += t[u].w; }
                else if ((u & 3) == 2) { s2.x += t[u].x; s2.y += t[u].y; s2.z += t[u].z; s2.w += t[u].w; }
                else { s3.x += t[u].x; s3.y += t[u].y; s3.z += t[u].z; s3.w += t[u].w; }
            }
        }
    }
    float4 r;
    r.x = (s0.x + s1.x) + (s2.x + s3.x);
    r.y = (s0.y + s1.y) + (s2.y + s3.y);
    r.z = (s0.z + s1.z) + (s2.z + s3.z);
    r.w = (s0.w + s1.w) + (s2.w + s3.w);
    a[(size_t)v * 4 + h] = r;
}

// ====== fin1: t=relu(dv*(a+g1)+b1); g2 = dv*(t@W2)  (in place over a) =====
__global__ void fin1_xform2_kernel(float* __restrict__ a,   // sums in, g2 out
                                   const float* __restrict__ g1,
                                   const float* __restrict__ dinv,
                                   const float* __restrict__ b1,
                                   const float* __restrict__ W2,
                                   int n) {
    __shared__ float W2s[HID * HID];
    W2s[threadIdx.x] = W2[threadIdx.x];   // blockDim == 256
    __syncthreads();

    int v = blockIdx.x * blockDim.x + threadIdx.x;
    if (v >= n) return;
    float dv = dinv[v];
    const float4* a4 = (const float4*)(a + (size_t)v * HID);
    const float4* s4 = (const float4*)(g1 + (size_t)v * HID);
    float t[HID];
#pragma unroll
    for (int q = 0; q < HID / 4; ++q) {
        float4 av = a4[q];
        float4 sv = s4[q];
        t[q * 4 + 0] = fmaxf(dv * (av.x + sv.x) + b1[q * 4 + 0], 0.0f);
        t[q * 4 + 1] = fmaxf(dv * (av.y + sv.y) + b1[q * 4 + 1], 0.0f);
        t[q * 4 + 2] = fmaxf(dv * (av.z + sv.z) + b1[q * 4 + 2], 0.0f);
        t[q * 4 + 3] = fmaxf(dv * (av.w + sv.w) + b1[q * 4 + 3], 0.0f);
    }
    float4* outp = (float4*)(a + (size_t)v * HID);
#pragma unroll
    for (int q = 0; q < HID / 4; ++q) {
        float4 o;
        float h[4];
#pragma unroll
        for (int r = 0; r < 4; ++r) {
            int j2 = q * 4 + r;
            float acc = 0.0f;
#pragma unroll
            for (int j = 0; j < HID; ++j) acc += t[j] * W2s[j * HID + j2];
            h[r] = acc * dv;
        }
        o.x = h[0]; o.y = h[1]; o.z = h[2]; o.w = h[3];
        outp[q] = o;
    }
}

// ===== layer-2 aggregation + finalize + bias ==============================
__global__ __launch_bounds__(256) void agg_fin_kernel(
        const int* __restrict__ row_start,
        const int* __restrict__ slots,
        const float4* __restrict__ g,      // g2, 4 x float4 per node
        const float* __restrict__ dinv,
        const float* __restrict__ b2,
        float4* __restrict__ out, int n) {
    int v = blockIdx.x * 64 + (threadIdx.x >> 2);
    int h = threadIdx.x & 3;
    if (v >= n) return;

    int rs = row_start[v], re = row_start[v + 1];
    float4 s0 = {0.f,0.f,0.f,0.f}, s1 = s0, s2 = s0, s3 = s0;

    for (int k = rs; k < re; k += BATCH) {
        int e[BATCH];
#pragma unroll
        for (int u = 0; u < BATCH; ++u)
            e[u] = slots[min(k + u, re - 1)];
        float4 t[BATCH];
#pragma unroll
        for (int u = 0; u < BATCH; ++u)
            t[u] = g[(size_t)e[u] * 4 + h];
#pragma unroll
        for (int u = 0; u < BATCH; ++u) {
            if (k + u < re) {
                if ((u & 3) == 0) { s0.x += t[u].x; s0.y += t[u].y; s0.z += t[u].z; s0.w += t[u].w; }
                else if ((u & 3) == 1) { s1.x += t[u].x; s1.y += t[u].y; s1.z += t[u].z; s1.w += t[u].w; }
                else if ((u & 3) == 2) { s2.x += t[u].x; s2.y += t[u].y; s2.z += t[u].z; s2.w += t[u].w; }
                else { s3.x += t[u].x; s3.y += t[u].y; s3.z += t[u].z; s3.w += t[u].w; }
            }
        }
    }
    float4 acc;
    acc.x = (s0.x + s1.x) + (s2.x + s3.x);
    acc.y = (s0.y + s1.y) + (s2.y + s3.y);
    acc.z = (s0.z + s1.z) + (s2.z + s3.z);
    acc.w = (s0.w + s1.w) + (s2.w + s3.w);

    float dv = dinv[v];
    float4 self = g[(size_t)v * 4 + h];
    float4 bb = ((const float4*)b2)[h];
    float4 o;
    o.x = dv * (acc.x + self.x) + bb.x;
    o.y = dv * (acc.y + self.y) + bb.y;
    o.z = dv * (acc.z + self.z) + bb.z;
    o.w = dv * (acc.w + self.w) + bb.w;
    out[(size_t)v * 4 + h] = o;
}

// ========================= fallback (atomic) path ==========================
__global__ void deg_kernel(const int* __restrict__ dst,
                           float* __restrict__ deg, int E) {
    int e = blockIdx.x * blockDim.x + threadIdx.x;
    if (e < E) atomicAdd(&deg[dst[e]], 1.0f);
}

__global__ void dinv_kernel(float* __restrict__ deg, int n) {
    int v = blockIdx.x * blockDim.x + threadIdx.x;
    if (v < n) deg[v] = rsqrtf(deg[v] + 1.0f);
}

__global__ void agg_kernel(const int* __restrict__ src,
                           const int* __restrict__ dst,
                           const float* __restrict__ g,
                           float* __restrict__ acc, long long total) {
    long long i = (long long)blockIdx.x * blockDim.x + threadIdx.x;
    if (i >= total) return;
    int e = (int)(i >> 4);
    int j = (int)(i & 15);
    atomicAdd(&acc[(size_t)dst[e] * HID + j], g[(size_t)src[e] * HID + j]);
}

__global__ void fin1_xform2_nolds_kernel(float* __restrict__ a1,
                                         const float* __restrict__ g1,
                                         const float* __restrict__ dinv,
                                         const float* __restrict__ b1,
                                         const float* __restrict__ W2,
                                         int n) {
    int v = blockIdx.x * blockDim.x + threadIdx.x;
    if (v >= n) return;
    float dv = dinv[v];
    const float4* a4 = (const float4*)(a1 + (size_t)v * HID);
    const float4* s4 = (const float4*)(g1 + (size_t)v * HID);
    float t[HID];
#pragma unroll
    for (int q = 0; q < HID / 4; ++q) {
        float4 av = a4[q];
        float4 sv = s4[q];
        t[q * 4 + 0] = fmaxf(dv * (av.x + sv.x) + b1[q * 4 + 0], 0.0f);
        t[q * 4 + 1] = fmaxf(dv * (av.y + sv.y) + b1[q * 4 + 1], 0.0f);
        t[q * 4 + 2] = fmaxf(dv * (av.z + sv.z) + b1[q * 4 + 2], 0.0f);
        t[q * 4 + 3] = fmaxf(dv * (av.w + sv.w) + b1[q * 4 + 3], 0.0f);
    }
    float4* outp = (float4*)(a1 + (size_t)v * HID);
#pragma unroll
    for (int q = 0; q < HID / 4; ++q) {
        float4 o;
        float h[4];
#pragma unroll
        for (int r = 0; r < 4; ++r) {
            int j2 = q * 4 + r;
            float acc = 0.0f;
#pragma unroll
            for (int j = 0; j < HID; ++j) acc += t[j] * W2[j * HID + j2];
            h[r] = acc * dv;
        }
        o.x = h[0]; o.y = h[1]; o.z = h[2]; o.w = h[3];
        outp[q] = o;
    }
}

__global__ void fin2_kernel(float* __restrict__ out,
                            const float* __restrict__ g2,
                            const float* __restrict__ dinv,
                            const float* __restrict__ b2, int n) {
    int v = blockIdx.x * blockDim.x + threadIdx.x;
    if (v >= n) return;
    float dv = dinv[v];
    float4* o4 = (float4*)(out + (size_t)v * HID);
    const float4* g4 = (const float4*)(g2 + (size_t)v * HID);
#pragma unroll
    for (int q = 0; q < HID / 4; ++q) {
        float4 ov = o4[q];
        float4 gv = g4[q];
        float4 r;
        r.x = dv * (ov.x + gv.x) + b2[q * 4 + 0];
        r.y = dv * (ov.y + gv.y) + b2[q * 4 + 1];
        r.z = dv * (ov.z + gv.z) + b2[q * 4 + 2];
        r.w = dv * (ov.w + gv.w) + b2[q * 4 + 3];
        o4[q] = r;
    }
}

// ===========================================================================
extern "C" void kernel_launch(void* const* d_in, const int* in_sizes, int n_in,
                              void* d_out, int out_size, void* d_ws, size_t ws_size,
                              hipStream_t stream) {
    const float* x  = (const float*)d_in[0];
    const int*   ei = (const int*)d_in[1];     // int32 (JAX x64 disabled)
    const float* W1 = (const float*)d_in[2];
    const float* b1 = (const float*)d_in[3];
    const float* W2 = (const float*)d_in[4];
    const float* b2 = (const float*)d_in[5];
    float* out = (float*)d_out;

    const int n = in_sizes[0] / N_FEAT;         // 100000
    const int E = in_sizes[1] / 2;              // 3200000
    const int* src = ei;
    const int* dst = ei + E;

    const int B = 256;
    size_t nal = ((size_t)n + 255) & ~(size_t)255;
    const int K = (n + NPB - 1) / NPB;          // 782 fine buckets

    // ws: binned(E) | ctrl | row_start(nal+64) | dinv(nal) | g1(16nal) | a(16nal)
    size_t need = ((size_t)E + CTRL_INTS + 34 * nal + 64) * sizeof(int);

    if (ws_size >= need && K <= KMAX) {
        int*   binned    = (int*)d_ws;                   // E
        int*   ctrl      = binned + E;                   // CTRL_INTS
        int*   bcnt      = ctrl;                         // 1024
        int*   bstart    = ctrl + 1024;                  // 1056
        int*   gcursorF  = ctrl + 2080;                  // 1024
        int*   row_start = ctrl + CTRL_INTS;             // nal + 64
        float* dinv      = (float*)(row_start + nal + 64);
        float* g1        = dinv + nal;                   // 16*nal (64B rows)
        float* a         = g1 + 16 * nal;                // 16*nal (sums -> g2)

        hipMemsetAsync(bcnt, 0, 1024 * sizeof(int), stream);

        bhist_kernel<<<512, 256, 0, stream>>>(dst, bcnt, E, K);
        bscan_kernel<<<1, KMAX, 0, stream>>>(bcnt, bstart, gcursorF, K, E);

        int nblk = (E + 256 * EPT - 1) / (256 * EPT);
        bin_kernel<<<nblk, 256, 0, stream>>>(src, dst, gcursorF, binned, E);

        sort_kernel<<<K, 256, 0, stream>>>(bstart, binned, row_start, dinv, n, E);

        xform1_kernel<<<(n + B - 1) / B, B, 0, stream>>>(x, W1, dinv, g1, n);

        int nb64 = (n + 63) / 64;
        agg_raw_kernel<<<nb64, 256, 0, stream>>>(row_start, binned,
                                                 (const float4*)g1, (float4*)a, n);
        fin1_xform2_kernel<<<(n + B - 1) / B, B, 0, stream>>>(a, g1, dinv, b1, W2, n);
        agg_fin_kernel<<<nb64, 256, 0, stream>>>(row_start, binned,
                                                 (const float4*)a, dinv, b2,
                                                 (float4*)out, n);
    } else {
        // fallback: proven atomic path
        float* w   = (float*)d_ws;
        float* deg = w;                  // nal  (becomes dinv)
        float* a1  = w + nal;            // 16*nal (becomes g2)
        float* g1  = a1 + 16 * nal;      // 16*nal

        hipMemsetAsync(d_ws, 0, (nal * 17) * sizeof(float), stream);
        hipMemsetAsync(d_out, 0, (size_t)out_size * sizeof(float), stream);

        deg_kernel<<<(E + B - 1) / B, B, 0, stream>>>(dst, deg, E);
        dinv_kernel<<<(n + B - 1) / B, B, 0, stream>>>(deg, n);
        xform1_kernel<<<(n + B - 1) / B, B, 0, stream>>>(x, W1, deg, g1, n);
        long long total = (long long)E * HID;
        agg_kernel<<<(int)((total + B - 1) / B), B, 0, stream>>>(src, dst, g1, a1, total);
        fin1_xform2_nolds_kernel<<<(n + B - 1) / B, B, 0, stream>>>(a1, g1, deg, b1, W2, n);
        agg_kernel<<<(int)((total + B - 1) / B), B, 0, stream>>>(src, dst, a1, out, total);
        fin2_kernel<<<(n + B - 1) / B, B, 0, stream>>>(out, a1, deg, b2, n);
    }
}

// Round 14
// 185.799 us; speedup vs baseline: 4.2114x; 1.0603x over previous
//
#include <hip/hip_runtime.h>

#define N_FEAT 128
#define HID 16
#define NPB 128          // nodes per fine bucket (7-bit local dst)
#define KMAX 1024        // max fine buckets (K = 782 here)
#define SEGCAP 8192      // max edges per fine bucket in sort LDS
#define EPT 4            // edges per thread in bin_kernel (1024 thr, 782 blocks)
#define BATCH 16         // parallel gathers per batch in agg kernels

// ctrl region (ints): bcnt@0(1024) | bstart@1024(1056) | gcursorF@2080(1024)
#define CTRL_INTS 3584

// ================= fine histogram (dst>>7) ================================
__global__ void bhist_kernel(const int* __restrict__ dst,
                             int* __restrict__ bcnt, int E, int K) {
    __shared__ int h[KMAX];
    for (int i = threadIdx.x; i < KMAX; i += 256) h[i] = 0;
    __syncthreads();
    for (long long e = (long long)blockIdx.x * 256 + threadIdx.x; e < E;
         e += (long long)gridDim.x * 256)
        atomicAdd(&h[dst[e] >> 7], 1);
    __syncthreads();
    for (int i = threadIdx.x; i < K; i += 256)
        if (h[i]) atomicAdd(&bcnt[i], h[i]);
}

// ================= scan of fine-bucket counts =============================
__global__ void bscan_kernel(const int* __restrict__ bcnt,
                             int* __restrict__ bstart,
                             int* __restrict__ gcursorF, int K, int E) {
    __shared__ int l[KMAX];
    int t = threadIdx.x;
    int v = (t < K) ? bcnt[t] : 0;
    l[t] = v;
    __syncthreads();
    for (int off = 1; off < KMAX; off <<= 1) {
        int tmp = (t >= off) ? l[t - off] : 0;
        __syncthreads();
        l[t] += tmp;
        __syncthreads();
    }
    int excl = l[t] - v;
    bstart[t]   = excl;          // == E for t >= K
    gcursorF[t] = excl;
    if (t == 0) bstart[KMAX] = E;
}

// ===== one-level binning: 1024 threads, EPT=4 (same 4096 edges/block,
//       same one-reservation-per-bucket-per-block structure as proven) =====
__global__ void bin_kernel(const int* __restrict__ src,
                           const int* __restrict__ dst,
                           int* __restrict__ gcursor,
                           int* __restrict__ binned, int E) {
    __shared__ int rcnt[KMAX];
    __shared__ int rbase[KMAX];
    int base = blockIdx.x * (1024 * EPT);
    if (base >= E) return;

    for (int i = threadIdx.x; i < KMAX; i += 1024) rcnt[i] = 0;
    __syncthreads();

    int myb[EPT], myoff[EPT], mypack[EPT];
#pragma unroll
    for (int q = 0; q < EPT; ++q) {
        int e = base + q * 1024 + threadIdx.x;
        myb[q] = -1;
        if (e < E) {
            int d = dst[e], s = src[e];
            int b = d >> 7;
            myb[q]    = b;
            mypack[q] = ((d & 127) << 17) | s;
            myoff[q]  = atomicAdd(&rcnt[b], 1);
        }
    }
    __syncthreads();
    for (int i = threadIdx.x; i < KMAX; i += 1024) {
        int c = rcnt[i];
        if (c > 0) rbase[i] = atomicAdd(&gcursor[i], c);
    }
    __syncthreads();
#pragma unroll
    for (int q = 0; q < EPT; ++q)
        if (myb[q] >= 0) binned[rbase[myb[q]] + myoff[q]] = mypack[q];
}

// ===== per-fine-bucket counting sort (in place, 1024 thr) + row_start + dinv
__global__ void sort_kernel(const int* __restrict__ bstart,
                            int* __restrict__ binned,
                            int* __restrict__ row_start,
                            float* __restrict__ dinv, int n, int E) {
    __shared__ int seg[SEGCAP];
    __shared__ int cnt[NPB];
    __shared__ int excl[NPB];
    __shared__ int cur[NPB];
    int b = blockIdx.x;
    int rs = bstart[b], re = bstart[b + 1];
    int m = re - rs;
    if (m > SEGCAP) m = SEGCAP;
    int t = threadIdx.x;

    if (t < NPB) cnt[t] = 0;
    __syncthreads();

    for (int k = t; k < m; k += 1024) {
        int p = binned[rs + k];
        seg[k] = p;
        atomicAdd(&cnt[p >> 17], 1);
    }
    __syncthreads();

    if (t < NPB) excl[t] = cnt[t];
    __syncthreads();
    for (int off = 1; off < NPB; off <<= 1) {
        int v = (t < NPB && t >= off) ? excl[t - off] : 0;
        __syncthreads();
        if (t < NPB) excl[t] += v;
        __syncthreads();
    }

    int vbase = b * NPB;
    if (t < NPB) {
        int e0 = excl[t] - cnt[t];
        cur[t] = e0;
        int v = vbase + t;
        if (v < n) {
            row_start[v] = rs + e0;
            dinv[v] = rsqrtf((float)cnt[t] + 1.0f);
        }
    }
    if (b == 0 && t == 0) row_start[n] = E;
    __syncthreads();

    for (int k = t; k < m; k += 1024) {
        int p = seg[k];
        int pos = rs + atomicAdd(&cur[p >> 17], 1);
        binned[pos] = p & 0x1FFFF;                 // sorted src
    }
}

// ================= xform1: g1[v,:] = (x[v,:] @ W1) * dinv[v] ==============
__global__ void xform1_kernel(const float* __restrict__ x,
                              const float* __restrict__ W1,
                              const float* __restrict__ dinv,
                              float* __restrict__ g1, int n) {
    __shared__ float Ws[N_FEAT * HID];
    for (int i = threadIdx.x; i < N_FEAT * HID; i += blockDim.x)
        Ws[i] = W1[i];
    __syncthreads();

    int v = blockIdx.x * blockDim.x + threadIdx.x;
    if (v >= n) return;

    float acc[HID];
#pragma unroll
    for (int j = 0; j < HID; ++j) acc[j] = 0.0f;

    const float4* xr = (const float4*)(x + (size_t)v * N_FEAT);
#pragma unroll
    for (int k4 = 0; k4 < N_FEAT / 4; ++k4) {
        float4 xv = xr[k4];
        int k = k4 * 4;
#pragma unroll
        for (int j = 0; j < HID; ++j) {
            acc[j] += xv.x * Ws[(k + 0) * HID + j]
                    + xv.y * Ws[(k + 1) * HID + j]
                    + xv.z * Ws[(k + 2) * HID + j]
                    + xv.w * Ws[(k + 3) * HID + j];
        }
    }
    float dv = dinv[v];
    float4* outp = (float4*)(g1 + (size_t)v * HID);
#pragma unroll
    for (int q = 0; q < HID / 4; ++q) {
        float4 o;
        o.x = acc[q * 4 + 0] * dv;
        o.y = acc[q * 4 + 1] * dv;
        o.z = acc[q * 4 + 2] * dv;
        o.w = acc[q * 4 + 3] * dv;
        outp[q] = o;
    }
}

// ===== layer-1 aggregation: 4 lanes/node, 16 predicated parallel gathers ===
__global__ __launch_bounds__(256) void agg_raw_kernel(
        const int* __restrict__ row_start,
        const int* __restrict__ slots,
        const float4* __restrict__ g,      // 4 x float4 per node (64B row)
        float4* __restrict__ a, int n) {
    int v = blockIdx.x * 64 + (threadIdx.x >> 2);
    int h = threadIdx.x & 3;
    if (v >= n) return;

    int rs = row_start[v], re = row_start[v + 1];
    float4 s0 = {0.f,0.f,0.f,0.f}, s1 = s0, s2 = s0, s3 = s0;

    for (int k = rs; k < re; k += BATCH) {
        int e[BATCH];
#pragma unroll
        for (int u = 0; u < BATCH; ++u)
            e[u] = slots[min(k + u, re - 1)];
        float4 t[BATCH];
#pragma unroll
        for (int u = 0; u < BATCH; ++u)
            t[u] = g[(size_t)e[u] * 4 + h];
#pragma unroll
        for (int u = 0; u < BATCH; ++u) {
            if (k + u < re) {
                if ((u & 3) == 0) { s0.x += t[u].x; s0.y += t[u].y; s0.z += t[u].z; s0.w += t[u].w; }
                else if ((u & 3) == 1) { s1.x += t[u].x; s1.y += t[u].y; s1.z += t[u].z; s1.w += t[u].w; }
                else if ((u & 3) == 2) { s2.x += t[u].x; s2.y += t[u].y; s2.z += t[u].z; s2.w += t[u].w; }
                else { s3.x += t[u].x; s3.y += t[u].y; s3.z += t[u].z; s3.w += t[u].w; }
            }
        }
    }
    float4 r;
    r.x = (s0.x + s1.x) + (s2.x + s3.x);
    r.y = (s0.y + s1.y) + (s2.y + s3.y);
    r.z = (s0.z + s1.z) + (s2.z + s3.z);
    r.w = (s0.w + s1.w) + (s2.w + s3.w);
    a[(size_t)v * 4 + h] = r;
}

// ====== fin1: t=relu(dv*(a+g1)+b1); g2 = dv*(t@W2)  (in place over a) =====
__global__ void fin1_xform2_kernel(float* __restrict__ a,   // sums in, g2 out
                                   const float* __restrict__ g1,
                                   const float* __restrict__ dinv,
                                   const float* __restrict__ b1,
                                   const float* __restrict__ W2,
                                   int n) {
    __shared__ float W2s[HID * HID];
    W2s[threadIdx.x] = W2[threadIdx.x];   // blockDim == 256
    __syncthreads();

    int v = blockIdx.x * blockDim.x + threadIdx.x;
    if (v >= n) return;
    float dv = dinv[v];
    const float4* a4 = (const float4*)(a + (size_t)v * HID);
    const float4* s4 = (const float4*)(g1 + (size_t)v * HID);
    float t[HID];
#pragma unroll
    for (int q = 0; q < HID / 4; ++q) {
        float4 av = a4[q];
        float4 sv = s4[q];
        t[q * 4 + 0] = fmaxf(dv * (av.x + sv.x) + b1[q * 4 + 0], 0.0f);
        t[q * 4 + 1] = fmaxf(dv * (av.y + sv.y) + b1[q * 4 + 1], 0.0f);
        t[q * 4 + 2] = fmaxf(dv * (av.z + sv.z) + b1[q * 4 + 2], 0.0f);
        t[q * 4 + 3] = fmaxf(dv * (av.w + sv.w) + b1[q * 4 + 3], 0.0f);
    }
    float4* outp = (float4*)(a + (size_t)v * HID);
#pragma unroll
    for (int q = 0; q < HID / 4; ++q) {
        float4 o;
        float h[4];
#pragma unroll
        for (int r = 0; r < 4; ++r) {
            int j2 = q * 4 + r;
            float acc = 0.0f;
#pragma unroll
            for (int j = 0; j < HID; ++j) acc += t[j] * W2s[j * HID + j2];
            h[r] = acc * dv;
        }
        o.x = h[0]; o.y = h[1]; o.z = h[2]; o.w = h[3];
        outp[q] = o;
    }
}

// ===== layer-2 aggregation + finalize + bias ==============================
__global__ __launch_bounds__(256) void agg_fin_kernel(
        const int* __restrict__ row_start,
        const int* __restrict__ slots,
        const float4* __restrict__ g,      // g2, 4 x float4 per node
        const float* __restrict__ dinv,
        const float* __restrict__ b2,
        float4* __restrict__ out, int n) {
    int v = blockIdx.x * 64 + (threadIdx.x >> 2);
    int h = threadIdx.x & 3;
    if (v >= n) return;

    int rs = row_start[v], re = row_start[v + 1];
    float4 s0 = {0.f,0.f,0.f,0.f}, s1 = s0, s2 = s0, s3 = s0;

    for (int k = rs; k < re; k += BATCH) {
        int e[BATCH];
#pragma unroll
        for (int u = 0; u < BATCH; ++u)
            e[u] = slots[min(k + u, re - 1)];
        float4 t[BATCH];
#pragma unroll
        for (int u = 0; u < BATCH; ++u)
            t[u] = g[(size_t)e[u] * 4 + h];
#pragma unroll
        for (int u = 0; u < BATCH; ++u) {
            if (k + u < re) {
                if ((u & 3) == 0) { s0.x += t[u].x; s0.y += t[u].y; s0.z += t[u].z; s0.w += t[u].w; }
                else if ((u & 3) == 1) { s1.x += t[u].x; s1.y += t[u].y; s1.z += t[u].z; s1.w += t[u].w; }
                else if ((u & 3) == 2) { s2.x += t[u].x; s2.y += t[u].y; s2.z += t[u].z; s2.w += t[u].w; }
                else { s3.x += t[u].x; s3.y += t[u].y; s3.z += t[u].z; s3.w += t[u].w; }
            }
        }
    }
    float4 acc;
    acc.x = (s0.x + s1.x) + (s2.x + s3.x);
    acc.y = (s0.y + s1.y) + (s2.y + s3.y);
    acc.z = (s0.z + s1.z) + (s2.z + s3.z);
    acc.w = (s0.w + s1.w) + (s2.w + s3.w);

    float dv = dinv[v];
    float4 self = g[(size_t)v * 4 + h];
    float4 bb = ((const float4*)b2)[h];
    float4 o;
    o.x = dv * (acc.x + self.x) + bb.x;
    o.y = dv * (acc.y + self.y) + bb.y;
    o.z = dv * (acc.z + self.z) + bb.z;
    o.w = dv * (acc.w + self.w) + bb.w;
    out[(size_t)v * 4 + h] = o;
}

// ========================= fallback (atomic) path ==========================
__global__ void deg_kernel(const int* __restrict__ dst,
                           float* __restrict__ deg, int E) {
    int e = blockIdx.x * blockDim.x + threadIdx.x;
    if (e < E) atomicAdd(&deg[dst[e]], 1.0f);
}

__global__ void dinv_kernel(float* __restrict__ deg, int n) {
    int v = blockIdx.x * blockDim.x + threadIdx.x;
    if (v < n) deg[v] = rsqrtf(deg[v] + 1.0f);
}

__global__ void agg_kernel(const int* __restrict__ src,
                           const int* __restrict__ dst,
                           const float* __restrict__ g,
                           float* __restrict__ acc, long long total) {
    long long i = (long long)blockIdx.x * blockDim.x + threadIdx.x;
    if (i >= total) return;
    int e = (int)(i >> 4);
    int j = (int)(i & 15);
    atomicAdd(&acc[(size_t)dst[e] * HID + j], g[(size_t)src[e] * HID + j]);
}

__global__ void fin1_xform2_nolds_kernel(float* __restrict__ a1,
                                         const float* __restrict__ g1,
                                         const float* __restrict__ dinv,
                                         const float* __restrict__ b1,
                                         const float* __restrict__ W2,
                                         int n) {
    int v = blockIdx.x * blockDim.x + threadIdx.x;
    if (v >= n) return;
    float dv = dinv[v];
    const float4* a4 = (const float4*)(a1 + (size_t)v * HID);
    const float4* s4 = (const float4*)(g1 + (size_t)v * HID);
    float t[HID];
#pragma unroll
    for (int q = 0; q < HID / 4; ++q) {
        float4 av = a4[q];
        float4 sv = s4[q];
        t[q * 4 + 0] = fmaxf(dv * (av.x + sv.x) + b1[q * 4 + 0], 0.0f);
        t[q * 4 + 1] = fmaxf(dv * (av.y + sv.y) + b1[q * 4 + 1], 0.0f);
        t[q * 4 + 2] = fmaxf(dv * (av.z + sv.z) + b1[q * 4 + 2], 0.0f);
        t[q * 4 + 3] = fmaxf(dv * (av.w + sv.w) + b1[q * 4 + 3], 0.0f);
    }
    float4* outp = (float4*)(a1 + (size_t)v * HID);
#pragma unroll
    for (int q = 0; q < HID / 4; ++q) {
        float4 o;
        float h[4];
#pragma unroll
        for (int r = 0; r < 4; ++r) {
            int j2 = q * 4 + r;
            float acc = 0.0f;
#pragma unroll
            for (int j = 0; j < HID; ++j) acc += t[j] * W2[j * HID + j2];
            h[r] = acc * dv;
        }
        o.x = h[0]; o.y = h[1]; o.z = h[2]; o.w = h[3];
        outp[q] = o;
    }
}

__global__ void fin2_kernel(float* __restrict__ out,
                            const float* __restrict__ g2,
                            const float* __restrict__ dinv,
                            const float* __restrict__ b2, int n) {
    int v = blockIdx.x * blockDim.x + threadIdx.x;
    if (v >= n) return;
    float dv = dinv[v];
    float4* o4 = (float4*)(out + (size_t)v * HID);
    const float4* g4 = (const float4*)(g2 + (size_t)v * HID);
#pragma unroll
    for (int q = 0; q < HID / 4; ++q) {
        float4 ov = o4[q];
        float4 gv = g4[q];
        float4 r;
        r.x = dv * (ov.x + gv.x) + b2[q * 4 + 0];
        r.y = dv * (ov.y + gv.y) + b2[q * 4 + 1];
        r.z = dv * (ov.z + gv.z) + b2[q * 4 + 2];
        r.w = dv * (ov.w + gv.w) + b2[q * 4 + 3];
        o4[q] = r;
    }
}

// ===========================================================================
extern "C" void kernel_launch(void* const* d_in, const int* in_sizes, int n_in,
                              void* d_out, int out_size, void* d_ws, size_t ws_size,
                              hipStream_t stream) {
    const float* x  = (const float*)d_in[0];
    const int*   ei = (const int*)d_in[1];     // int32 (JAX x64 disabled)
    const float* W1 = (const float*)d_in[2];
    const float* b1 = (const float*)d_in[3];
    const float* W2 = (const float*)d_in[4];
    const float* b2 = (const float*)d_in[5];
    float* out = (float*)d_out;

    const int n = in_sizes[0] / N_FEAT;         // 100000
    const int E = in_sizes[1] / 2;              // 3200000
    const int* src = ei;
    const int* dst = ei + E;

    const int B = 256;
    size_t nal = ((size_t)n + 255) & ~(size_t)255;
    const int K = (n + NPB - 1) / NPB;          // 782 fine buckets

    // ws: binned(E) | ctrl | row_start(nal+64) | dinv(nal) | g1(16nal) | a(16nal)
    size_t need = ((size_t)E + CTRL_INTS + 34 * nal + 64) * sizeof(int);

    if (ws_size >= need && K <= KMAX) {
        int*   binned    = (int*)d_ws;                   // E
        int*   ctrl      = binned + E;                   // CTRL_INTS
        int*   bcnt      = ctrl;                         // 1024
        int*   bstart    = ctrl + 1024;                  // 1056
        int*   gcursorF  = ctrl + 2080;                  // 1024
        int*   row_start = ctrl + CTRL_INTS;             // nal + 64
        float* dinv      = (float*)(row_start + nal + 64);
        float* g1        = dinv + nal;                   // 16*nal (64B rows)
        float* a         = g1 + 16 * nal;                // 16*nal (sums -> g2)

        hipMemsetAsync(bcnt, 0, 1024 * sizeof(int), stream);

        bhist_kernel<<<512, 256, 0, stream>>>(dst, bcnt, E, K);
        bscan_kernel<<<1, KMAX, 0, stream>>>(bcnt, bstart, gcursorF, K, E);

        int nblk = (E + 1024 * EPT - 1) / (1024 * EPT);  // 782 blocks
        bin_kernel<<<nblk, 1024, 0, stream>>>(src, dst, gcursorF, binned, E);

        sort_kernel<<<K, 1024, 0, stream>>>(bstart, binned, row_start, dinv, n, E);

        xform1_kernel<<<(n + B - 1) / B, B, 0, stream>>>(x, W1, dinv, g1, n);

        int nb64 = (n + 63) / 64;
        agg_raw_kernel<<<nb64, 256, 0, stream>>>(row_start, binned,
                                                 (const float4*)g1, (float4*)a, n);
        fin1_xform2_kernel<<<(n + B - 1) / B, B, 0, stream>>>(a, g1, dinv, b1, W2, n);
        agg_fin_kernel<<<nb64, 256, 0, stream>>>(row_start, binned,
                                                 (const float4*)a, dinv, b2,
                                                 (float4*)out, n);
    } else {
        // fallback: proven atomic path
        float* w   = (float*)d_ws;
        float* deg = w;                  // nal  (becomes dinv)
        float* a1  = w + nal;            // 16*nal (becomes g2)
        float* g1  = a1 + 16 * nal;      // 16*nal

        hipMemsetAsync(d_ws, 0, (nal * 17) * sizeof(float), stream);
        hipMemsetAsync(d_out, 0, (size_t)out_size * sizeof(float), stream);

        deg_kernel<<<(E + B - 1) / B, B, 0, stream>>>(dst, deg, E);
        dinv_kernel<<<(n + B - 1) / B, B, 0, stream>>>(deg, n);
        xform1_kernel<<<(n + B - 1) / B, B, 0, stream>>>(x, W1, deg, g1, n);
        long long total = (long long)E * HID;
        agg_kernel<<<(int)((total + B - 1) / B), B, 0, stream>>>(src, dst, g1, a1, total);
        fin1_xform2_nolds_kernel<<<(n + B - 1) / B, B, 0, stream>>>(a1, g1, deg, b1, W2, n);
        agg_kernel<<<(int)((total + B - 1) / B), B, 0, stream>>>(src, dst, a1, out, total);
        fin2_kernel<<<(n + B - 1) / B, B, 0, stream>>>(out, a1, deg, b2, n);
    }
}